// Round 7
// baseline (50.331 us; speedup 1.0000x reference)
//
#include <hip/hip_runtime.h>

// Problem constants (match reference)
#define PNX 432
#define PNY 496
#define PNC 64
#define PLANE (PNY * PNX)   // 214272 = 837*256

typedef float f32x4 __attribute__((ext_vector_type(4)));

#define CSPLIT 4                 // channel slices (blockIdx.y)
#define CPERS (PNC / CSPLIT)     // 16 channels per slice
#define GPERS (CPERS / 4)        // 4 float4 groups per slice

// ---------------- init: map = -1, zrow = 0 ----------------
__global__ void pp_init(int4* __restrict__ map4, float* __restrict__ zrow, int n4) {
    int t = blockIdx.x * blockDim.x + threadIdx.x;
    if (t < n4) map4[t] = make_int4(-1, -1, -1, -1);
    if (blockIdx.x == 0 && threadIdx.x < PNC) zrow[threadIdx.x] = 0.0f;
}

// Scatter pillar index p into map at its global cell (cells unique).
__global__ void pp_scatter_map(const int4* __restrict__ coords,
                               int* __restrict__ map, int P) {
    int p = blockIdx.x * blockDim.x + threadIdx.x;
    if (p >= P) return;
    int4 c = coords[p];              // (b, z, y, x)
    int gidx = c.x * PLANE + c.y + c.z * PNX + c.w;
    map[gidx] = p;
}

// ---------------- gather ----------------
// Grid (837, CSPLIT) x 256. Thread: 4 consecutive cells x 16 channels.
// Branch-free zrow pointer select; f32x4 row loads; 4x4 register
// transpose; plain f32x4 stores -> 1KB contiguous per wave-store.
__global__ void pp_gather(const float* __restrict__ feat,
                          const int* __restrict__ map,
                          const float* __restrict__ zrow,
                          float* __restrict__ out, int n4) {
    int t = blockIdx.x * blockDim.x + threadIdx.x;   // cell4 index
    if (t >= n4) return;
    int cell0 = t * 4;
    int b = cell0 / PLANE;
    int spat = cell0 - b * PLANE;
    int cbase = blockIdx.y * CPERS;

    int4 pm = *reinterpret_cast<const int4*>(map + cell0);
    const float* s0 = ((pm.x >= 0) ? (feat + (size_t)pm.x * PNC) : zrow) + cbase;
    const float* s1 = ((pm.y >= 0) ? (feat + (size_t)pm.y * PNC) : zrow) + cbase;
    const float* s2 = ((pm.z >= 0) ? (feat + (size_t)pm.z * PNC) : zrow) + cbase;
    const float* s3 = ((pm.w >= 0) ? (feat + (size_t)pm.w * PNC) : zrow) + cbase;
    const f32x4* fp0 = reinterpret_cast<const f32x4*>(s0);
    const f32x4* fp1 = reinterpret_cast<const f32x4*>(s1);
    const f32x4* fp2 = reinterpret_cast<const f32x4*>(s2);
    const f32x4* fp3 = reinterpret_cast<const f32x4*>(s3);

    float* outp = out + (size_t)b * PNC * PLANE + (size_t)cbase * PLANE + spat;

    #pragma unroll
    for (int g = 0; g < GPERS; ++g) {                // 4 channels per group
        f32x4 r0 = fp0[g];
        f32x4 r1 = fp1[g];
        f32x4 r2 = fp2[g];
        f32x4 r3 = fp3[g];
        // transpose: output channel holds (cell0..cell0+3)
        f32x4 o0 = {r0.x, r1.x, r2.x, r3.x};
        f32x4 o1 = {r0.y, r1.y, r2.y, r3.y};
        f32x4 o2 = {r0.z, r1.z, r2.z, r3.z};
        f32x4 o3 = {r0.w, r1.w, r2.w, r3.w};
        float* o = outp + (size_t)(g * 4) * PLANE;
        *reinterpret_cast<f32x4*>(o) = o0;
        *reinterpret_cast<f32x4*>(o + PLANE) = o1;
        *reinterpret_cast<f32x4*>(o + 2 * PLANE) = o2;
        *reinterpret_cast<f32x4*>(o + 3 * PLANE) = o3;
    }
}

// ---------------- fallback path (ws too small) ----------------

__global__ void pp_zero_out(f32x4* __restrict__ out4, size_t n4) {
    size_t t = (size_t)blockIdx.x * blockDim.x + threadIdx.x;
    size_t stride = (size_t)gridDim.x * blockDim.x;
    const f32x4 z = {0.f, 0.f, 0.f, 0.f};
    for (size_t i = t; i < n4; i += stride) out4[i] = z;
}

__global__ void pp_scatter_direct(const float* __restrict__ feat,
                                  const int4* __restrict__ coords,
                                  float* __restrict__ out, int P) {
    int t = blockIdx.x * blockDim.x + threadIdx.x;
    int p = t >> 6;
    int c = t & 63;
    if (p >= P) return;
    int4 co = coords[p];
    size_t oidx = ((size_t)(co.x * PNC + c)) * PLANE + co.y + co.z * PNX + co.w;
    out[oidx] = feat[p * PNC + c];
}

extern "C" void kernel_launch(void* const* d_in, const int* in_sizes, int n_in,
                              void* d_out, int out_size, void* d_ws, size_t ws_size,
                              hipStream_t stream) {
    const float* feat = (const float*)d_in[0];
    const int4* coords = (const int4*)d_in[1];
    float* out = (float*)d_out;

    const int P = in_sizes[0] / PNC;                 // 64000
    const int B = out_size / (PNC * PLANE);          // 4
    const int ncells = B * PLANE;                    // 857088
    const size_t mapBytes = (size_t)ncells * sizeof(int);   // 16B-aligned
    const size_t needBytes = mapBytes + PNC * sizeof(float);

    if (ws_size >= needBytes) {
        int* map = (int*)d_ws;
        float* zrow = (float*)((char*)d_ws + mapBytes);
        int n4 = ncells / 4;                         // 214272
        pp_init<<<(n4 + 255) / 256, 256, 0, stream>>>((int4*)map, zrow, n4);
        pp_scatter_map<<<(P + 255) / 256, 256, 0, stream>>>(coords, map, P);
        dim3 grid((n4 + 255) / 256, CSPLIT);
        pp_gather<<<grid, 256, 0, stream>>>(feat, map, zrow, out, n4);
    } else {
        // Fallback: zero-fill + direct scatter (correct but more HBM traffic)
        size_t n4 = (size_t)out_size / 4;
        pp_zero_out<<<2048, 256, 0, stream>>>((f32x4*)out, n4);
        int total = P * PNC;
        pp_scatter_direct<<<(total + 255) / 256, 256, 0, stream>>>(feat, coords, out, P);
    }
}

// Round 8
// 48.962 us; speedup vs baseline: 1.0280x; 1.0280x over previous
//
#include <hip/hip_runtime.h>

// Problem constants (match reference)
#define PNX 432
#define PNY 496
#define PNC 64
#define PLANE (PNY * PNX)   // 214272 = 837*256

typedef float f32x4 __attribute__((ext_vector_type(4)));

#define CSPLIT 4                 // channel slices (blockIdx.y)
#define CPERS (PNC / CSPLIT)     // 16 channels per slice
#define GPERS (CPERS / 4)        // 4 float4 groups per slice

// ---------------- init: map = -1, zrow = 0 ----------------
__global__ void pp_init(int4* __restrict__ map4, float* __restrict__ zrow, int n4) {
    int t = blockIdx.x * blockDim.x + threadIdx.x;
    if (t < n4) map4[t] = make_int4(-1, -1, -1, -1);
    if (blockIdx.x == 0 && threadIdx.x < PNC) zrow[threadIdx.x] = 0.0f;
}

// Scatter pillar index p into map at its global cell (cells unique).
__global__ void pp_scatter_map(const int4* __restrict__ coords,
                               int* __restrict__ map, int P) {
    int p = blockIdx.x * blockDim.x + threadIdx.x;
    if (p >= P) return;
    int4 c = coords[p];              // (b, z, y, x)
    int gidx = c.x * PLANE + c.y + c.z * PNX + c.w;
    map[gidx] = p;
}

// ---------------- gather ----------------
// Grid (3348, CSPLIT) x 256. One thread per cell, 16 channels per slice.
// Keeps R5's load shape (one contiguous row segment per thread, branch-free
// zrow select) but cuts write streams per wave from 64 to 16 planes.
__global__ void pp_gather(const float* __restrict__ feat,
                          const int* __restrict__ map,
                          const float* __restrict__ zrow,
                          float* __restrict__ out, int ncells) {
    int cell = blockIdx.x * blockDim.x + threadIdx.x;
    if (cell >= ncells) return;
    int b = cell / PLANE;
    int spat = cell - b * PLANE;
    int cbase = blockIdx.y * CPERS;
    int pm = map[cell];

    const float* src = ((pm >= 0) ? (feat + (size_t)pm * PNC) : zrow) + cbase;
    const f32x4* fp = reinterpret_cast<const f32x4*>(src);

    f32x4 r[GPERS];
    #pragma unroll
    for (int g = 0; g < GPERS; ++g) r[g] = fp[g];

    float* o = out + (size_t)b * PNC * PLANE + (size_t)cbase * PLANE + spat;
    #pragma unroll
    for (int g = 0; g < GPERS; ++g) {
        o[(size_t)(4 * g + 0) * PLANE] = r[g].x;
        o[(size_t)(4 * g + 1) * PLANE] = r[g].y;
        o[(size_t)(4 * g + 2) * PLANE] = r[g].z;
        o[(size_t)(4 * g + 3) * PLANE] = r[g].w;
    }
}

// ---------------- fallback path (ws too small) ----------------

__global__ void pp_zero_out(f32x4* __restrict__ out4, size_t n4) {
    size_t t = (size_t)blockIdx.x * blockDim.x + threadIdx.x;
    size_t stride = (size_t)gridDim.x * blockDim.x;
    const f32x4 z = {0.f, 0.f, 0.f, 0.f};
    for (size_t i = t; i < n4; i += stride) out4[i] = z;
}

__global__ void pp_scatter_direct(const float* __restrict__ feat,
                                  const int4* __restrict__ coords,
                                  float* __restrict__ out, int P) {
    int t = blockIdx.x * blockDim.x + threadIdx.x;
    int p = t >> 6;
    int c = t & 63;
    if (p >= P) return;
    int4 co = coords[p];
    size_t oidx = ((size_t)(co.x * PNC + c)) * PLANE + co.y + co.z * PNX + co.w;
    out[oidx] = feat[p * PNC + c];
}

extern "C" void kernel_launch(void* const* d_in, const int* in_sizes, int n_in,
                              void* d_out, int out_size, void* d_ws, size_t ws_size,
                              hipStream_t stream) {
    const float* feat = (const float*)d_in[0];
    const int4* coords = (const int4*)d_in[1];
    float* out = (float*)d_out;

    const int P = in_sizes[0] / PNC;                 // 64000
    const int B = out_size / (PNC * PLANE);          // 4
    const int ncells = B * PLANE;                    // 857088
    const size_t mapBytes = (size_t)ncells * sizeof(int);   // 16B-aligned
    const size_t needBytes = mapBytes + PNC * sizeof(float);

    if (ws_size >= needBytes) {
        int* map = (int*)d_ws;
        float* zrow = (float*)((char*)d_ws + mapBytes);
        int n4 = ncells / 4;                         // 214272
        pp_init<<<(n4 + 255) / 256, 256, 0, stream>>>((int4*)map, zrow, n4);
        pp_scatter_map<<<(P + 255) / 256, 256, 0, stream>>>(coords, map, P);
        dim3 grid((ncells + 255) / 256, CSPLIT);
        pp_gather<<<grid, 256, 0, stream>>>(feat, map, zrow, out, ncells);
    } else {
        // Fallback: zero-fill + direct scatter (correct but more HBM traffic)
        size_t n4 = (size_t)out_size / 4;
        pp_zero_out<<<2048, 256, 0, stream>>>((f32x4*)out, n4);
        int total = P * PNC;
        pp_scatter_direct<<<(total + 255) / 256, 256, 0, stream>>>(feat, coords, out, P);
    }
}

// Round 9
// 46.290 us; speedup vs baseline: 1.0873x; 1.0577x over previous
//
#include <hip/hip_runtime.h>

// Problem constants (match reference)
#define PNX 432
#define PNY 496
#define PNC 64
#define PLANE (PNY * PNX)     // 214272 = 837*256
#define BPP   (PLANE / 256)   // 837 blocks per batch-plane

typedef float f32x4 __attribute__((ext_vector_type(4)));

// ---------------- init: map = -1, zrow = 0 ----------------
__global__ void pp_init(int4* __restrict__ map4, float* __restrict__ zrow, int n4) {
    int t = blockIdx.x * blockDim.x + threadIdx.x;
    if (t < n4) map4[t] = make_int4(-1, -1, -1, -1);
    if (blockIdx.x == 0 && threadIdx.x < PNC) zrow[threadIdx.x] = 0.0f;
}

// Scatter pillar index p into map at its global cell (cells unique).
__global__ void pp_scatter_map(const int4* __restrict__ coords,
                               int* __restrict__ map, int P) {
    int p = blockIdx.x * blockDim.x + threadIdx.x;
    if (p >= P) return;
    int4 c = coords[p];              // (b, z, y, x)
    int gidx = c.x * PLANE + c.y + c.z * PNX + c.w;
    map[gidx] = p;
}

// ---------------- gather with LDS transpose ----------------
// Block = 256 threads = 256 consecutive cells (never straddles a batch).
// Each thread: contiguous row preload (R5's good load shape), then two
// 32-channel LDS rounds turning them into 1KB-contiguous per-wave stores.
__global__ void __launch_bounds__(256)
pp_gather(const float* __restrict__ feat,
          const int* __restrict__ map,
          const float* __restrict__ zrow,
          float* __restrict__ out) {
    __shared__ float lds[32][260];                   // 33,280 B

    const int tid = threadIdx.x;
    const int i = tid & 63;                          // lane
    const int w = tid >> 6;                          // wave in block
    const int b = blockIdx.x / BPP;
    const int spat0 = (blockIdx.x % BPP) * 256;
    const int cell = blockIdx.x * 256 + tid;

    int pm = map[cell];
    const float* src = (pm >= 0) ? (feat + (size_t)pm * PNC) : zrow;
    const f32x4* fp = reinterpret_cast<const f32x4*>(src);

    f32x4 r[16];
    #pragma unroll
    for (int m = 0; m < 16; ++m) r[m] = fp[m];       // whole row in regs

    float* obase = out + ((size_t)b * PNC) * PLANE + spat0 + 4 * i;

    #pragma unroll
    for (int rr = 0; rr < 2; ++rr) {                 // two 32-channel rounds
        // write my cell's 32 channels as a column (lane stride 1: no conflicts)
        #pragma unroll
        for (int k = 0; k < 8; ++k) {
            f32x4 v = r[8 * rr + k];
            lds[4 * k + 0][tid] = v.x;
            lds[4 * k + 1][tid] = v.y;
            lds[4 * k + 2][tid] = v.z;
            lds[4 * k + 3][tid] = v.w;
        }
        __syncthreads();
        // read 4 consecutive cells of one channel; wave covers 256 cells = 1KB
        #pragma unroll
        for (int g = 0; g < 8; ++g) {
            int cl = g * 4 + w;                      // local channel 0..31
            f32x4 v = *reinterpret_cast<const f32x4*>(&lds[cl][4 * i]);
            *reinterpret_cast<f32x4*>(obase + (size_t)(32 * rr + cl) * PLANE) = v;
        }
        __syncthreads();
    }
}

// ---------------- fallback path (ws too small) ----------------

__global__ void pp_zero_out(f32x4* __restrict__ out4, size_t n4) {
    size_t t = (size_t)blockIdx.x * blockDim.x + threadIdx.x;
    size_t stride = (size_t)gridDim.x * blockDim.x;
    const f32x4 z = {0.f, 0.f, 0.f, 0.f};
    for (size_t i = t; i < n4; i += stride) out4[i] = z;
}

__global__ void pp_scatter_direct(const float* __restrict__ feat,
                                  const int4* __restrict__ coords,
                                  float* __restrict__ out, int P) {
    int t = blockIdx.x * blockDim.x + threadIdx.x;
    int p = t >> 6;
    int c = t & 63;
    if (p >= P) return;
    int4 co = coords[p];
    size_t oidx = ((size_t)(co.x * PNC + c)) * PLANE + co.y + co.z * PNX + co.w;
    out[oidx] = feat[p * PNC + c];
}

extern "C" void kernel_launch(void* const* d_in, const int* in_sizes, int n_in,
                              void* d_out, int out_size, void* d_ws, size_t ws_size,
                              hipStream_t stream) {
    const float* feat = (const float*)d_in[0];
    const int4* coords = (const int4*)d_in[1];
    float* out = (float*)d_out;

    const int P = in_sizes[0] / PNC;                 // 64000
    const int B = out_size / (PNC * PLANE);          // 4
    const int ncells = B * PLANE;                    // 857088 = 3348*256
    const size_t mapBytes = (size_t)ncells * sizeof(int);   // 16B-aligned
    const size_t needBytes = mapBytes + PNC * sizeof(float);

    if (ws_size >= needBytes && (ncells % 256) == 0) {
        int* map = (int*)d_ws;
        float* zrow = (float*)((char*)d_ws + mapBytes);
        int n4 = ncells / 4;                         // 214272
        pp_init<<<(n4 + 255) / 256, 256, 0, stream>>>((int4*)map, zrow, n4);
        pp_scatter_map<<<(P + 255) / 256, 256, 0, stream>>>(coords, map, P);
        pp_gather<<<ncells / 256, 256, 0, stream>>>(feat, map, zrow, out);
    } else {
        // Fallback: zero-fill + direct scatter (correct but more HBM traffic)
        size_t n4 = (size_t)out_size / 4;
        pp_zero_out<<<2048, 256, 0, stream>>>((f32x4*)out, n4);
        int total = P * PNC;
        pp_scatter_direct<<<(total + 255) / 256, 256, 0, stream>>>(feat, coords, out, P);
    }
}

// Round 10
// 44.404 us; speedup vs baseline: 1.1335x; 1.0425x over previous
//
#include <hip/hip_runtime.h>

// Problem constants (match reference)
#define PNX 432
#define PNY 496
#define PNC 64
#define PLANE (PNY * PNX)   // 214272 = 837*256

typedef float f32x4 __attribute__((ext_vector_type(4)));

// ---------------- scatter + zrow init ----------------
// Scatter pillar index p into map at its global cell (cells unique).
// Also zeroes the 64-float zrow (read by gather for empty cells).
// NOTE: map is NEVER cleared — gather self-validates entries against
// coords, so poison/stale values are rejected (or, for stale entries
// from a previous identical call, are already correct).
__global__ void pp_scatter_map(const int4* __restrict__ coords,
                               int* __restrict__ map,
                               float* __restrict__ zrow, int P) {
    int p = blockIdx.x * blockDim.x + threadIdx.x;
    if (blockIdx.x == 0 && threadIdx.x < PNC) zrow[threadIdx.x] = 0.0f;
    if (p >= P) return;
    int4 c = coords[p];              // (b, z, y, x)
    int gidx = c.x * PLANE + c.y + c.z * PNX + c.w;
    map[gidx] = p;
}

// ---------------- gather (self-validating map) ----------------
// One thread per cell: map read, coords-validate, branch-free zrow
// select, 16 contiguous f32x4 row loads, 64 dword stores
// (256B contiguous per wave-store instruction). R5 structure.
__global__ void pp_gather(const float* __restrict__ feat,
                          const int* __restrict__ map,
                          const int4* __restrict__ coords,
                          const float* __restrict__ zrow,
                          float* __restrict__ out, int ncells, int P) {
    int cell = blockIdx.x * blockDim.x + threadIdx.x;
    if (cell >= ncells) return;
    int b = cell / PLANE;
    int spat = cell - b * PLANE;

    int pm = map[cell];
    unsigned upm = (unsigned)pm;
    int pms = (upm < (unsigned)P) ? pm : 0;          // safe index
    int4 c = coords[pms];                            // L2-resident (1MB)
    bool valid = (upm < (unsigned)P) &&
                 (c.x * PLANE + c.y + c.z * PNX + c.w == cell);

    const float* src = valid ? (feat + (size_t)pms * PNC) : zrow;
    const f32x4* fp = reinterpret_cast<const f32x4*>(src);

    f32x4 r[16];
    #pragma unroll
    for (int g = 0; g < 16; ++g) r[g] = fp[g];

    float* o = out + (size_t)b * PNC * PLANE + spat;
    #pragma unroll
    for (int g = 0; g < 16; ++g) {
        o[(size_t)(4 * g + 0) * PLANE] = r[g].x;
        o[(size_t)(4 * g + 1) * PLANE] = r[g].y;
        o[(size_t)(4 * g + 2) * PLANE] = r[g].z;
        o[(size_t)(4 * g + 3) * PLANE] = r[g].w;
    }
}

// ---------------- fallback path (ws too small) ----------------

__global__ void pp_zero_out(f32x4* __restrict__ out4, size_t n4) {
    size_t t = (size_t)blockIdx.x * blockDim.x + threadIdx.x;
    size_t stride = (size_t)gridDim.x * blockDim.x;
    const f32x4 z = {0.f, 0.f, 0.f, 0.f};
    for (size_t i = t; i < n4; i += stride) out4[i] = z;
}

__global__ void pp_scatter_direct(const float* __restrict__ feat,
                                  const int4* __restrict__ coords,
                                  float* __restrict__ out, int P) {
    int t = blockIdx.x * blockDim.x + threadIdx.x;
    int p = t >> 6;
    int c = t & 63;
    if (p >= P) return;
    int4 co = coords[p];
    size_t oidx = ((size_t)(co.x * PNC + c)) * PLANE + co.y + co.z * PNX + co.w;
    out[oidx] = feat[p * PNC + c];
}

extern "C" void kernel_launch(void* const* d_in, const int* in_sizes, int n_in,
                              void* d_out, int out_size, void* d_ws, size_t ws_size,
                              hipStream_t stream) {
    const float* feat = (const float*)d_in[0];
    const int4* coords = (const int4*)d_in[1];
    float* out = (float*)d_out;

    const int P = in_sizes[0] / PNC;                 // 64000
    const int B = out_size / (PNC * PLANE);          // 4
    const int ncells = B * PLANE;                    // 857088
    const size_t mapBytes = (size_t)ncells * sizeof(int);   // 16B-aligned
    const size_t needBytes = mapBytes + PNC * sizeof(float);

    if (ws_size >= needBytes) {
        int* map = (int*)d_ws;
        float* zrow = (float*)((char*)d_ws + mapBytes);
        pp_scatter_map<<<(P + 255) / 256, 256, 0, stream>>>(coords, map, zrow, P);
        pp_gather<<<(ncells + 255) / 256, 256, 0, stream>>>(feat, map, coords,
                                                            zrow, out, ncells, P);
    } else {
        // Fallback: zero-fill + direct scatter (correct but more HBM traffic)
        size_t n4 = (size_t)out_size / 4;
        pp_zero_out<<<2048, 256, 0, stream>>>((f32x4*)out, n4);
        int total = P * PNC;
        pp_scatter_direct<<<(total + 255) / 256, 256, 0, stream>>>(feat, coords, out, P);
    }
}